// Round 1
// baseline (184.392 us; speedup 1.0000x reference)
//
#include <hip/hip_runtime.h>
#include <stdint.h>

// AttentionHead: out = softmax(QK^T/sqrt(dk) - 1e15*mask) @ V, with Q/K/V = inputs @ W{q,k,v}
// B=4 S=2048 E=1024 D=128. Strategy: bf16 MFMA everywhere, flash-style fused attention.

#define SEQ   2048
#define EDIM  1024
#define DDIM  128
#define QSCALE 0.08838834764831845f   // 1/sqrt(128)

typedef unsigned short u16;
using short8 = __attribute__((ext_vector_type(8))) short;   // 8 x bf16 (4 VGPR) MFMA frag
using f32x4  = __attribute__((ext_vector_type(4))) float;

__device__ __forceinline__ u16 f2bf(float x) {              // f32 -> bf16 RNE
    uint32_t u = __float_as_uint(x);
    return (u16)((u + 0x7fffu + ((u >> 16) & 1u)) >> 16);
}

// async global->LDS 16B per lane; LDS dst = wave-uniform base + lane*16 (linear).
__device__ __forceinline__ void gld16(const void* gsrc, void* lds_dst) {
    __builtin_amdgcn_global_load_lds(
        (const __attribute__((address_space(1))) uint32_t*)(uintptr_t)gsrc,
        (__attribute__((address_space(3))) uint32_t*)(uint32_t)(uintptr_t)lds_dst,
        16, 0, 0);
}

// ---------------- kernel 1: W f32 [1024][128] -> Wt bf16 [3][128][1024] (transposed) ----
__global__ __launch_bounds__(256) void wprep_kernel(
    const float* __restrict__ Wq, const float* __restrict__ Wk, const float* __restrict__ Wv,
    u16* __restrict__ Wt)
{
    __shared__ u16 tl[64][65];
    const int t = blockIdx.x;            // 96 blocks = 3 mats * 32 tiles(16k x 2n)
    const int wsel = t >> 5;
    const int tile = t & 31;
    const int k0 = (tile >> 1) * 64;
    const int n0 = (tile & 1) * 64;
    const float* W = (wsel == 0) ? Wq : ((wsel == 1) ? Wk : Wv);
#pragma unroll
    for (int it = 0; it < 16; ++it) {
        const int idx = it * 256 + threadIdx.x;
        const int r = idx >> 6, c = idx & 63;         // r=k-local, c=n-local (coalesced read)
        tl[c][r] = f2bf(W[(size_t)(k0 + r) * DDIM + n0 + c]);
    }
    __syncthreads();
    u16* Wtp = Wt + (size_t)wsel * DDIM * EDIM;
#pragma unroll
    for (int it = 0; it < 16; ++it) {
        const int idx = it * 256 + threadIdx.x;
        const int r = idx >> 6, c = idx & 63;         // r=n-local, c=k-local (coalesced write)
        Wtp[(size_t)(n0 + r) * EDIM + k0 + c] = tl[r][c];
    }
}

// ---------------- kernel 2: projections. C[8192][128] = A[8192][1024] @ W ----------------
// grid (128 m-tiles, 3 matrices), 256 thr (4 waves x 16 rows). Tile 64x128, BK=64.
// Outputs: wm=0 -> Q bf16 [8192][128]; wm=1 -> K bf16 [8192][128]; wm=2 -> Vt bf16 [B][128][S].
__global__ __launch_bounds__(256, 2) void proj_kernel(
    const float* __restrict__ Ain, const u16* __restrict__ Wtb,
    u16* __restrict__ Qb, u16* __restrict__ Kb, u16* __restrict__ Vtb)
{
    __shared__ __align__(16) uint8_t smem[24576];   // A 8KB @0, Wt 16KB @8192 (both XOR-swizzled)
    const int tid = threadIdx.x;
    const int w = tid >> 6, lane = tid & 63;
    const int lq = lane & 15, lg = lane >> 4;
    const int m0 = blockIdx.x * 64;
    const int wm = blockIdx.y;
    const u16* Wt = Wtb + (size_t)wm * DDIM * EDIM;

    f32x4 acc[8] = {};

#pragma unroll 1
    for (int kt = 0; kt < 16; ++kt) {
        const int k0 = kt * 64;
        // Wt tile [128 n][64 k] -> LDS, linear dest + inverse-swizzled source (granule ^= n&7)
#pragma unroll
        for (int i = 0; i < 4; ++i) {
            const int G = i * 256 + tid;
            const int n = G >> 3, c = G & 7;
            gld16(Wt + (size_t)n * EDIM + k0 + (size_t)((c ^ (n & 7)) * 8),
                  smem + 8192 + i * 4096 + w * 1024);
        }
        // A tile [64 m][64 k] f32 -> bf16 reg-staged, swizzled ds_write_b128
#pragma unroll
        for (int i = 0; i < 2; ++i) {
            const int G = i * 256 + tid;
            const int row = G >> 3, c = G & 7;
            const float* s2 = Ain + (size_t)(m0 + row) * EDIM + k0 + (c ^ (row & 7)) * 8;
            const f32x4 a0 = *(const f32x4*)s2;
            const f32x4 a1 = *(const f32x4*)(s2 + 4);
            short8 v;
            v[0] = (short)f2bf(a0[0]); v[1] = (short)f2bf(a0[1]);
            v[2] = (short)f2bf(a0[2]); v[3] = (short)f2bf(a0[3]);
            v[4] = (short)f2bf(a1[0]); v[5] = (short)f2bf(a1[1]);
            v[6] = (short)f2bf(a1[2]); v[7] = (short)f2bf(a1[3]);
            *(short8*)(smem + row * 128 + (c << 4)) = v;
        }
        __syncthreads();
#pragma unroll
        for (int ks = 0; ks < 2; ++ks) {
            const int arow = w * 16 + lq;
            const short8 af = *(const short8*)(smem + arow * 128 + ((((ks << 2) + lg) ^ (arow & 7)) << 4));
#pragma unroll
            for (int nf = 0; nf < 8; ++nf) {
                const int nrow = nf * 16 + lq;
                const short8 bfv = *(const short8*)(smem + 8192 + nrow * 128 + ((((ks << 2) + lg) ^ (nrow & 7)) << 4));
                acc[nf] = __builtin_amdgcn_mfma_f32_16x16x32_bf16(af, bfv, acc[nf], 0, 0, 0);
            }
        }
        __syncthreads();
    }

    // epilogue via LDS retile for coalesced bf16 stores. C-frag: row=(lg*4+r), col=nf*16+lq.
    if (wm < 2) {
        u16* Ot = (u16*)smem;   // [64][128]
#pragma unroll
        for (int nf = 0; nf < 8; ++nf)
#pragma unroll
            for (int r = 0; r < 4; ++r)
                Ot[(size_t)(w * 16 + lg * 4 + r) * 128 + nf * 16 + lq] = f2bf(acc[nf][r]);
        __syncthreads();
        u16* dst = (wm == 0 ? Qb : Kb) + (size_t)m0 * 128;
#pragma unroll
        for (int i = 0; i < 4; ++i) {
            const int idx = (i * 256 + tid) * 8;
            *(short8*)(dst + idx) = *(const short8*)((const u16*)smem + idx);
        }
    } else {
        // V transposed: LDS [128 d][64 s] with granule swizzle ((srow>>3) ^ (d&7))
#pragma unroll
        for (int nf = 0; nf < 8; ++nf)
#pragma unroll
            for (int r = 0; r < 4; ++r) {
                const int srow = w * 16 + lg * 4 + r;
                const int dcol = nf * 16 + lq;
                *(u16*)(smem + dcol * 128 + (((srow >> 3) ^ (dcol & 7)) << 4) + (srow & 7) * 2) = f2bf(acc[nf][r]);
            }
        __syncthreads();
        const int b = m0 >> 11;
        const int s0b = m0 & 2047;
        u16* dst = Vtb + (size_t)b * DDIM * SEQ;
#pragma unroll
        for (int i = 0; i < 4; ++i) {
            const int idx = i * 256 + tid;          // granule id, 1024 total
            const int dd = idx >> 3, c = idx & 7;
            const short8 v2 = *(const short8*)(smem + dd * 128 + ((c ^ (dd & 7)) << 4));
            *(short8*)(dst + (size_t)dd * SEQ + s0b + c * 8) = v2;
        }
    }
}

// ---------------- kernel 3: fused flash attention ----------------------------------------
// grid 512 (16 q-rows per block), 4 waves; wave w covers kv quarter [w*512,(w+1)*512), KVB=32.
// Per-wave LDS tiles (no block barriers in main loop). 4-way combine at the end.
__global__ __launch_bounds__(256, 2) void flash_kernel(
    const int* __restrict__ mask,
    const u16* __restrict__ Qb, const u16* __restrict__ Kb, const u16* __restrict__ Vtb,
    float* __restrict__ out)
{
    __shared__ __align__(16) uint8_t smem[69632];  // [4 waves][K 8KB | V 8KB] @0..64KB, P 4x1KB @65536
    __shared__ float ml_m[4][16], ml_l[4][16], recipL[16];

    const int tid = threadIdx.x;
    const int w = tid >> 6, lane = tid & 63;
    const int lq = lane & 15, lg = lane >> 4;

    const int qt = blockIdx.x;                 // 0..511
    const int b = qt >> 7;                     // 128 q-tiles per batch
    const int q0 = (qt & 127) << 4;
    const size_t qrow0 = (size_t)b * SEQ + q0;

    const u16* Qp = Qb + qrow0 * 128;
    const u16* Kp = Kb + (size_t)b * SEQ * 128;
    const u16* Vp = Vtb + (size_t)b * DDIM * SEQ;
    const int* mp = mask + ((size_t)b * SEQ + q0) * SEQ;

    // Q fragments in regs: lane holds Q[q=lq][k=ks*32+lg*8 .. +8]
    short8 qf[4];
#pragma unroll
    for (int ks = 0; ks < 4; ++ks)
        qf[ks] = *(const short8*)(Qp + (size_t)lq * 128 + ks * 32 + lg * 8);

    f32x4 acc[8] = {};                         // O accum: row=lg*4+r, col=df*16+lq
    float mrow[4], lrow[4];
#pragma unroll
    for (int r = 0; r < 4; ++r) { mrow[r] = -1e30f; lrow[r] = 0.0f; }

    uint8_t* kvbase = smem + w * 16384;

#pragma unroll 1
    for (int t = 0; t < 16; ++t) {
        const int kv0 = w * 512 + t * 32;
        // ensure prior iteration's ds_reads finished before overwriting LDS
        asm volatile("s_waitcnt lgkmcnt(0)" ::: "memory");
        // stage K tile [32 kv][128 d] (granule ^= kvrow&7)
#pragma unroll
        for (int i = 0; i < 8; ++i) {
            const int G = i * 64 + lane;
            const int row = G >> 4, c = G & 15;
            gld16(Kp + (size_t)(kv0 + row) * 128 + (c ^ (row & 7)) * 8,
                  kvbase + i * 1024);
        }
        // stage V tile [128 d][32 kv] (granule ^= (d^(d>>2))&3)
#pragma unroll
        for (int i = 0; i < 8; ++i) {
            const int G = i * 64 + lane;
            const int dd = G >> 2, c = G & 3;
            gld16(Vp + (size_t)dd * SEQ + kv0 + (c ^ ((dd ^ (dd >> 2)) & 3)) * 8,
                  kvbase + 8192 + i * 1024);
        }
        // mask (coalesced 64B per 16-lane group)
        int mv[2][4];
#pragma unroll
        for (int nf = 0; nf < 2; ++nf)
#pragma unroll
            for (int r = 0; r < 4; ++r)
                mv[nf][r] = mp[(size_t)(lg * 4 + r) * SEQ + kv0 + nf * 16 + lq];

        asm volatile("s_waitcnt vmcnt(0)" ::: "memory");

        // S = Q K^T : C-frag row=q(lg*4+r), col=kv(nf*16+lq)
        f32x4 sacc[2] = {};
#pragma unroll
        for (int ks = 0; ks < 4; ++ks) {
#pragma unroll
            for (int nf = 0; nf < 2; ++nf) {
                const int krow = nf * 16 + lq;
                const short8 kf = *(const short8*)(kvbase + krow * 256 + ((((ks << 2) + lg) ^ (krow & 7)) << 4));
                sacc[nf] = __builtin_amdgcn_mfma_f32_16x16x32_bf16(qf[ks], kf, sacc[nf], 0, 0, 0);
            }
        }

        float sv[2][4], tm[4];
#pragma unroll
        for (int nf = 0; nf < 2; ++nf)
#pragma unroll
            for (int r = 0; r < 4; ++r)
                sv[nf][r] = sacc[nf][r] * QSCALE - 1e15f * (float)mv[nf][r];
#pragma unroll
        for (int r = 0; r < 4; ++r) tm[r] = fmaxf(sv[0][r], sv[1][r]);
#pragma unroll
        for (int d = 1; d < 16; d <<= 1)
#pragma unroll
            for (int r = 0; r < 4; ++r)
                tm[r] = fmaxf(tm[r], __shfl_xor(tm[r], d));

        float sf[4];
#pragma unroll
        for (int r = 0; r < 4; ++r) {
            const float mnew = fmaxf(mrow[r], tm[r]);
            sf[r] = __expf(mrow[r] - mnew);
            mrow[r] = mnew;
        }
        float p[2][4], rs[4];
#pragma unroll
        for (int nf = 0; nf < 2; ++nf)
#pragma unroll
            for (int r = 0; r < 4; ++r)
                p[nf][r] = __expf(sv[nf][r] - mrow[r]);
#pragma unroll
        for (int r = 0; r < 4; ++r) rs[r] = p[0][r] + p[1][r];
#pragma unroll
        for (int d = 1; d < 16; d <<= 1)
#pragma unroll
            for (int r = 0; r < 4; ++r)
                rs[r] += __shfl_xor(rs[r], d);
#pragma unroll
        for (int r = 0; r < 4; ++r) lrow[r] = lrow[r] * sf[r] + rs[r];
#pragma unroll
        for (int df = 0; df < 8; ++df)
#pragma unroll
            for (int r = 0; r < 4; ++r)
                acc[df][r] *= sf[r];

        // P -> per-wave LDS [16 q][32 kv] bf16 (granule ^= (q^(q>>2))&3), then PV
        uint8_t* pbase = smem + 65536 + w * 1024;
#pragma unroll
        for (int nf = 0; nf < 2; ++nf)
#pragma unroll
            for (int r = 0; r < 4; ++r) {
                const int row = lg * 4 + r, col = nf * 16 + lq;
                *(u16*)(pbase + row * 64 + ((((col >> 3) ^ ((row ^ (row >> 2)) & 3))) << 4) + (col & 7) * 2)
                    = f2bf(p[nf][r]);
            }
        const short8 pf = *(const short8*)(pbase + lq * 64 + ((lg ^ ((lq ^ (lq >> 2)) & 3)) << 4));
#pragma unroll
        for (int nf = 0; nf < 8; ++nf) {
            const int dd = nf * 16 + lq;
            const short8 vf = *(const short8*)(kvbase + 8192 + dd * 64 + ((lg ^ ((dd ^ (dd >> 2)) & 3)) << 4));
            acc[nf] = __builtin_amdgcn_mfma_f32_16x16x32_bf16(pf, vf, acc[nf], 0, 0, 0);
        }
    }

    // ---- combine 4 kv-quarters ----
    if (lq == 0) {
#pragma unroll
        for (int r = 0; r < 4; ++r) {
            ml_m[w][lg * 4 + r] = mrow[r];
            ml_l[w][lg * 4 + r] = lrow[r];
        }
    }
    __syncthreads();
    float Lg[4];
#pragma unroll
    for (int r = 0; r < 4; ++r) {
        const int row = lg * 4 + r;
        const float m0v = ml_m[0][row], m1v = ml_m[1][row], m2v = ml_m[2][row], m3v = ml_m[3][row];
        const float mm = fmaxf(fmaxf(m0v, m1v), fmaxf(m2v, m3v));
        Lg[r] = ml_l[0][row] * __expf(m0v - mm) + ml_l[1][row] * __expf(m1v - mm)
              + ml_l[2][row] * __expf(m2v - mm) + ml_l[3][row] * __expf(m3v - mm);
        const float s = __expf(mrow[r] - mm);
#pragma unroll
        for (int df = 0; df < 8; ++df) acc[df][r] *= s;
    }
    if (w == 0 && lq == 0) {
#pragma unroll
        for (int r = 0; r < 4; ++r) recipL[lg * 4 + r] = 1.0f / Lg[r];
    }
    // scaled partials -> LDS [4][16][128] f32 (reuses K/V area; all waves past loop)
    float* Ol = (float*)smem;
#pragma unroll
    for (int df = 0; df < 8; ++df)
#pragma unroll
        for (int r = 0; r < 4; ++r)
            Ol[(size_t)(w * 16 + lg * 4 + r) * 128 + df * 16 + lq] = acc[df][r];
    __syncthreads();

    {
        const int idx = tid * 8;
        const int row = idx >> 7, c0 = idx & 127;
        const float rl = recipL[row];
        f32x4 s0 = {}, s1 = {};
#pragma unroll
        for (int wv = 0; wv < 4; ++wv) {
            const float* p2 = Ol + (size_t)(wv * 16 + row) * 128 + c0;
            s0 += *(const f32x4*)p2;
            s1 += *(const f32x4*)(p2 + 4);
        }
        s0 *= rl; s1 *= rl;
        float* op = out + (qrow0 + row) * 128 + c0;
        *(f32x4*)op = s0;
        *(f32x4*)(op + 4) = s1;
    }
}

// ---------------- launcher ---------------------------------------------------------------
extern "C" void kernel_launch(void* const* d_in, const int* in_sizes, int n_in,
                              void* d_out, int out_size, void* d_ws, size_t ws_size,
                              hipStream_t stream) {
    (void)in_sizes; (void)n_in; (void)out_size; (void)ws_size;
    const float* inputs = (const float*)d_in[0];
    const int*   mask   = (const int*)d_in[1];
    const float* Wq     = (const float*)d_in[2];
    const float* Wk     = (const float*)d_in[3];
    const float* Wv     = (const float*)d_in[4];
    float* out = (float*)d_out;

    uint8_t* ws = (uint8_t*)d_ws;
    u16* Wtb = (u16*)ws;                        //  786,432 B  [3][128][1024] bf16
    u16* Qb  = (u16*)(ws + 786432);             // 2,097,152 B [8192][128] bf16
    u16* Kb  = (u16*)(ws + 2883584);            // 2,097,152 B
    u16* Vtb = (u16*)(ws + 4980736);            // 2,097,152 B [4][128][2048] bf16
    // total ws use: 7,077,888 B

    hipLaunchKernelGGL(wprep_kernel, dim3(96), dim3(256), 0, stream, Wq, Wk, Wv, Wtb);
    hipLaunchKernelGGL(proj_kernel, dim3(128, 3), dim3(256), 0, stream, inputs, Wtb, Qb, Kb, Vtb);
    hipLaunchKernelGGL(flash_kernel, dim3(512), dim3(256), 0, stream, mask, Qb, Kb, Vtb, out);
}